// Round 6
// baseline (154.194 us; speedup 1.0000x reference)
//
#include <hip/hip_runtime.h>
#include <math.h>

// Problem constants
#define S 64
#define F 10
#define K 7
#define D 512
#define HH 196   // H*H = 14*14
#define DT 128
#define NF (S*F)          // 640
#define NROWS_V (S*F*K)   // 4480
#define NROWS_A (S*K)     // 448
#define NOUT (S*K*F)      // 4480
#define MLP_R 8
#define NA_BLK (NROWS_A / MLP_R)   // 56
#define NV_BLK (NROWS_V / MLP_R)   // 560

// ---------------------------------------------------------------------------
// Kernel 1 (v4): fg[n][k][c] = (sum_hw feat[n][c][hw]*cam[n][k][hw]) / (cam_sum+1e-10)
// Pure register version: no feat staging, no inner-loop barriers.
// 1280 blocks (n x half) x 128 threads = 5 blocks/CU, 10 waves/CU.
// Thread owns channels c0 = half*256 + t and c0+128; acc[2][7] in registers;
// zero cross-lane reduction. Inner loop: 7 jj-blocks x 14 independent float4
// loads (14 KB/wave in flight) + 392 FMA vs cam read uniform from LDS.
// ---------------------------------------------------------------------------
__global__ __launch_bounds__(128) void fg_kernel(
    const float* __restrict__ feat, const float* __restrict__ cam,
    float* __restrict__ fg) {
  __shared__ float4 cam_lds[K * 49];   // 5,488 B
  __shared__ float inv_lds[K];

  const int t = threadIdx.x;
  const int lane = t & 63;
  const int n = blockIdx.x >> 1;
  const int half = blockIdx.x & 1;
  const int c0 = half * 256 + t;       // second channel: c0 + 128

  const float* camn = cam + (size_t)n * K * HH;

  // stage cam into LDS (343 float4, contiguous)
  for (int p = t; p < K * 49; p += 128)
    cam_lds[p] = reinterpret_cast<const float4*>(camn)[p];

  // cam sums -> inv_lds[k] (wave 0 butterfly)
  if (t < 64) {
    const bool act = lane < 49;
#pragma unroll
    for (int k = 0; k < K; ++k) {
      float4 cv = act ? *reinterpret_cast<const float4*>(camn + k * HH + 4 * lane)
                      : make_float4(0.f, 0.f, 0.f, 0.f);
      float s = cv.x + cv.y + cv.z + cv.w;
#pragma unroll
      for (int m = 32; m >= 1; m >>= 1) s += __shfl_xor(s, m, 64);
      if (lane == 0) inv_lds[k] = 1.0f / (s + 1e-10f);
    }
  }
  __syncthreads();

  const float4* row0 = reinterpret_cast<const float4*>(feat + ((size_t)n * D + c0) * HH);
  const float4* row1 = reinterpret_cast<const float4*>(feat + ((size_t)n * D + c0 + 128) * HH);

  float a0[K], a1[K];
#pragma unroll
  for (int k = 0; k < K; ++k) { a0[k] = 0.f; a1[k] = 0.f; }

  for (int jj = 0; jj < 49; jj += 7) {
    float4 f0[7], f1[7];
#pragma unroll
    for (int i = 0; i < 7; ++i) {
      f0[i] = row0[jj + i];
      f1[i] = row1[jj + i];
    }
#pragma unroll
    for (int i = 0; i < 7; ++i) {
#pragma unroll
      for (int k = 0; k < K; ++k) {
        const float4 cv = cam_lds[k * 49 + jj + i];
        a0[k] = fmaf(f0[i].x, cv.x, a0[k]);
        a0[k] = fmaf(f0[i].y, cv.y, a0[k]);
        a0[k] = fmaf(f0[i].z, cv.z, a0[k]);
        a0[k] = fmaf(f0[i].w, cv.w, a0[k]);
        a1[k] = fmaf(f1[i].x, cv.x, a1[k]);
        a1[k] = fmaf(f1[i].y, cv.y, a1[k]);
        a1[k] = fmaf(f1[i].z, cv.z, a1[k]);
        a1[k] = fmaf(f1[i].w, cv.w, a1[k]);
      }
    }
  }

  // coalesced writeback (consecutive t -> consecutive c within each k row)
  float* fgn = fg + (size_t)n * K * D;
#pragma unroll
  for (int k = 0; k < K; ++k) {
    const float iv = inv_lds[k];
    fgn[k * D + c0] = a0[k] * iv;
    fgn[k * D + c0 + 128] = a1[k] * iv;
  }
}

// ---------------------------------------------------------------------------
// Kernel 2: BOTH MLPs in one dispatch (unchanged).
// ---------------------------------------------------------------------------
__device__ __forceinline__ void fma4(float4& acc, float sx, const float4& wv) {
  acc.x += sx * wv.x; acc.y += sx * wv.y; acc.z += sx * wv.z; acc.w += sx * wv.w;
}

__global__ __launch_bounds__(256) void mlp2_kernel(
    const float* __restrict__ Xa, const float* __restrict__ Xv,
    const float* __restrict__ W1a, const float* __restrict__ b1a,
    const float* __restrict__ W2a, const float* __restrict__ b2a,
    const float* __restrict__ ga, const float* __restrict__ bna,
    const float* __restrict__ W1v, const float* __restrict__ b1v,
    const float* __restrict__ W2v, const float* __restrict__ b2v,
    const float* __restrict__ gv, const float* __restrict__ bnv,
    float* __restrict__ Ta, float* __restrict__ Tv) {
  __shared__ float xs[MLP_R * D];
  __shared__ float hs[MLP_R * DT];
  const int t = threadIdx.x;
  const int b = blockIdx.x;

  const float *X, *W1, *b1, *W2, *b2, *g, *bn;
  float* out;
  int r0;
  if (b < NA_BLK) {
    X = Xa; W1 = W1a; b1 = b1a; W2 = W2a; b2 = b2a; g = ga; bn = bna;
    out = Ta; r0 = b * MLP_R;
  } else {
    X = Xv; W1 = W1v; b1 = b1v; W2 = W2v; b2 = b2v; g = gv; bn = bnv;
    out = Tv; r0 = (b - NA_BLK) * MLP_R;
  }

  {
    const float4* src = reinterpret_cast<const float4*>(X + (size_t)r0 * D);
    float4* dst = reinterpret_cast<float4*>(xs);
#pragma unroll
    for (int i = 0; i < 4; ++i) dst[t + i * 256] = src[t + i * 256];
  }
  __syncthreads();

  const int j0 = (t & 31) * 4;
  const int rt = t >> 5;

  float4 a0 = *reinterpret_cast<const float4*>(b1 + j0);
  for (int d = 0; d < D; d += 4) {
    float4 xa = *reinterpret_cast<const float4*>(xs + rt * D + d);
    float4 w0 = *reinterpret_cast<const float4*>(W1 + (size_t)(d + 0) * DT + j0);
    float4 w1 = *reinterpret_cast<const float4*>(W1 + (size_t)(d + 1) * DT + j0);
    float4 w2 = *reinterpret_cast<const float4*>(W1 + (size_t)(d + 2) * DT + j0);
    float4 w3 = *reinterpret_cast<const float4*>(W1 + (size_t)(d + 3) * DT + j0);
    fma4(a0, xa.x, w0); fma4(a0, xa.y, w1); fma4(a0, xa.z, w2); fma4(a0, xa.w, w3);
  }
  a0.x = fmaxf(a0.x, 0.f); a0.y = fmaxf(a0.y, 0.f);
  a0.z = fmaxf(a0.z, 0.f); a0.w = fmaxf(a0.w, 0.f);
  *reinterpret_cast<float4*>(hs + rt * DT + j0) = a0;
  __syncthreads();

  float4 c0 = *reinterpret_cast<const float4*>(b2 + j0);
  for (int d = 0; d < DT; d += 4) {
    float4 xa = *reinterpret_cast<const float4*>(hs + rt * DT + d);
    float4 w0 = *reinterpret_cast<const float4*>(W2 + (size_t)(d + 0) * DT + j0);
    float4 w1 = *reinterpret_cast<const float4*>(W2 + (size_t)(d + 1) * DT + j0);
    float4 w2 = *reinterpret_cast<const float4*>(W2 + (size_t)(d + 2) * DT + j0);
    float4 w3 = *reinterpret_cast<const float4*>(W2 + (size_t)(d + 3) * DT + j0);
    fma4(c0, xa.x, w0); fma4(c0, xa.y, w1); fma4(c0, xa.z, w2); fma4(c0, xa.w, w3);
  }
  float4 gvv = *reinterpret_cast<const float4*>(g + j0);
  float4 bv = *reinterpret_cast<const float4*>(bn + j0);
  float4 o0;
  o0.x = c0.x * gvv.x + bv.x; o0.y = c0.y * gvv.y + bv.y;
  o0.z = c0.z * gvv.z + bv.z; o0.w = c0.w * gvv.w + bv.w;
  *reinterpret_cast<float4*>(out + (size_t)(r0 + rt) * DT + j0) = o0;
}

// ---------------------------------------------------------------------------
// Kernel 3: losses + masks (unchanged).
// ---------------------------------------------------------------------------
__global__ __launch_bounds__(256) void loss_kernel(
    const float* __restrict__ Ta, const float* __restrict__ Tv,
    const float* __restrict__ pred_a, const float* __restrict__ pred_v,
    const int* __restrict__ perm_idx, const int* __restrict__ cls_idx,
    float* __restrict__ out) {
  const int t = threadIdx.x;
  const int sub = t & 31;
  const int idx = blockIdx.x * 8 + (t >> 5);
  const int f = idx % F;
  const int k = (idx / F) % K;
  const int s = idx / (K * F);

  const int p = perm_idx[idx];
  const int c = cls_idx[idx];
  const int rowd = ((s ^ 1) * F + p) * K + c;

  float4 ta = reinterpret_cast<const float4*>(Ta)[(s * K + k) * 32 + sub];
  float4 tv = reinterpret_cast<const float4*>(Tv)[((s * F + f) * K + k) * 32 + sub];
  float4 td = reinterpret_cast<const float4*>(Tv)[rowd * 32 + sub];
  float d1 = 0.f, d2 = 0.f, e;
  e = ta.x - tv.x; d1 += e * e;
  e = ta.y - tv.y; d1 += e * e;
  e = ta.z - tv.z; d1 += e * e;
  e = ta.w - tv.w; d1 += e * e;
  e = ta.x - td.x; d2 += e * e;
  e = ta.y - td.y; d2 += e * e;
  e = ta.z - td.z; d2 += e * e;
  e = ta.w - td.w; d2 += e * e;
#pragma unroll
  for (int m = 16; m >= 1; m >>= 1) {
    d1 += __shfl_xor(d1, m, 64);
    d2 += __shfl_xor(d2, m, 64);
  }
  if (sub == 0) {
    float pa = pred_a[s * K + k];
    bool act = pa > 0.3f;
    int num = (int)floorf(pa * (float)F);
    float pvv = pred_v[(s * F + f) * K + k];
    float sg = 1.0f / (1.0f + expf(-pvv));
    bool mco = act && (sg > 0.3f);
    bool mdi = act && (f < num);
    float lco = d1 * (1.0f / 128.0f);
    float ldi = d2 * (1.0f / 128.0f);
    out[idx] = mco ? lco : 0.0f;
    out[NOUT + idx] = mdi ? ldi : 0.0f;
    out[2 * NOUT + idx] = mco ? 1.0f : 0.0f;
    out[3 * NOUT + idx] = mdi ? 1.0f : 0.0f;
  }
}

extern "C" void kernel_launch(void* const* d_in, const int* in_sizes, int n_in,
                              void* d_out, int out_size, void* d_ws, size_t ws_size,
                              hipStream_t stream) {
  const float* feat_a     = (const float*)d_in[0];
  const float* pred_a     = (const float*)d_in[1];
  const float* feat_v_raw = (const float*)d_in[2];
  const float* pred_v     = (const float*)d_in[3];
  const float* cam        = (const float*)d_in[4];
  const float* W1a = (const float*)d_in[5];
  const float* b1a = (const float*)d_in[6];
  const float* W2a = (const float*)d_in[7];
  const float* b2a = (const float*)d_in[8];
  const float* ga  = (const float*)d_in[9];
  const float* bna = (const float*)d_in[10];
  const float* W1v = (const float*)d_in[11];
  const float* b1v = (const float*)d_in[12];
  const float* W2v = (const float*)d_in[13];
  const float* b2v = (const float*)d_in[14];
  const float* gv  = (const float*)d_in[15];
  const float* bnv = (const float*)d_in[16];
  const int* perm_idx = (const int*)d_in[17];
  const int* cls_idx  = (const int*)d_in[18];
  float* out = (float*)d_out;

  // workspace layout (floats): fg[640*7*512] | Ta[448*128] | Tv[4480*128]
  float* ws = (float*)d_ws;
  float* fg = ws;
  float* Ta = fg + (size_t)NF * K * D;
  float* Tv = Ta + (size_t)NROWS_A * DT;

  fg_kernel<<<NF * 2, 128, 0, stream>>>(feat_v_raw, cam, fg);
  mlp2_kernel<<<NA_BLK + NV_BLK, 256, 0, stream>>>(
      feat_a, fg, W1a, b1a, W2a, b2a, ga, bna,
      W1v, b1v, W2v, b2v, gv, bnv, Ta, Tv);
  loss_kernel<<<NOUT / 8, 256, 0, stream>>>(Ta, Tv, pred_a, pred_v, perm_idx, cls_idx, out);
}